// Round 20
// baseline (31.960 us; speedup 1.0000x reference)
//
#include <hip/hip_runtime.h>

#define B_    2
#define NWQ   75
#define PQ    196
#define D_    64
#define WAY   5
#define SSUP  980                  // support patches per (b, way)
#define SPAD  992                  // padded to 31*32
#define ST32  31                   // 32-row support tiles
#define QI_PER_BLK 3
#define QCHUNKS 25                 // 75/3
#define QROWS 588                  // 3*196 query rows per chunk
#define QT32  19                   // ceil(588/32) query tiles of 32
#define NPC  (B_ * WAY * QCHUNKS)  // 250 blocks
#define NWAVES 8                   // waves per block (512 threads)

typedef __attribute__((ext_vector_type(8)))  short short8;   // 8 bf16 = 4 VGPR
typedef __attribute__((ext_vector_type(16))) float f32x16;   // 32x32 acc

__device__ __forceinline__ ushort f2bf(float f) {
    uint u = __builtin_bit_cast(uint, f);
    u = (u + 0x7FFFu + ((u >> 16) & 1u)) >> 16;
    return (ushort)u;
}

__device__ __forceinline__ short8 pack8(float4 a, float4 b) {
    short8 o;
    o[0] = (short)f2bf(a.x); o[1] = (short)f2bf(a.y);
    o[2] = (short)f2bf(a.z); o[3] = (short)f2bf(a.w);
    o[4] = (short)f2bf(b.x); o[5] = (short)f2bf(b.y);
    o[6] = (short)f2bf(b.z); o[7] = (short)f2bf(b.w);
    return o;
}

__device__ __forceinline__ float max3f(float a, float b, float c) {
    return fmaxf(fmaxf(a, b), c);
}

// Stage 16B units [u_begin, u_end) of the fp32 panel -> bf16 swizzled LDS.
__device__ __forceinline__ void stage_range(const float* __restrict__ Sfp,
                                            short8* __restrict__ ldsv,
                                            int tid, int u_begin, int u_end) {
    for (int u_idx = u_begin + tid; u_idx < u_end; u_idx += 512) {
        int r = u_idx >> 3, u = u_idx & 7;
        short8 o = {0,0,0,0,0,0,0,0};
        if (r < SSUP) {
            const float* src = Sfp + (size_t)r * D_ + u * 8;
            float4 f0 = *(const float4*)src;
            float4 f1 = *(const float4*)(src + 4);
            o = pack8(f0, f1);
        }
        ldsv[(r << 3) | (u ^ (r & 7))] = o;
    }
}

// Round-20: quarter-pipelined staging. Stage Q0 -> barrier -> {stage Q1 ||
// compute tiles of Q0} -> barrier -> ... -> compute Q3. Staging exposure
// drops ~5us -> ~1.3us. Main loop per tile-stream unchanged from r18/r19:
// 4x mfma_32x32x16 (K=64) -> 16->1 max3 screen -> 3-op insert.
template<int NT>
__device__ __forceinline__ void wave_path(
    short8* __restrict__ ldsv, int wid,
    const float* __restrict__ Qc, const float* __restrict__ Sfp,
    float* __restrict__ sums) {

    const int tid  = threadIdx.x;
    const int lane = tid & 63;
    const int l31  = lane & 31;               // A row / B col within tile
    const int h    = lane >> 5;               // k-half
    const int l7   = lane & 7;

    int u[4];
    #pragma unroll
    for (int j = 0; j < 4; ++j) u[j] = (j * 2 + h) ^ l7;   // swizzled 16B unit

    // ---- stage quarter 0 (rows 0..255) ----
    stage_range(Sfp, ldsv, tid, 0, 2048);

    // ---- B fragments: NT streams x 4 k-step frags (fp32 -> bf16 in regs) ----
    short8 bq[NT][4];
    int rows[NT];
    #pragma unroll
    for (int i = 0; i < NT; ++i) {
        int row = (wid + NWAVES * i) * 32 + l31;
        rows[i] = row;
        int rc = (row < QROWS) ? row : 0;     // clamp; discarded at epilogue
        const float* qrow = Qc + (size_t)rc * D_;
        #pragma unroll
        for (int j = 0; j < 4; ++j) {
            const float* s = qrow + h * 8 + j * 16;
            float4 f0 = *(const float4*)s;
            float4 f1 = *(const float4*)(s + 4);
            bq[i][j] = pack8(f0, f1);
        }
    }

    float t3[NT][3];
    #pragma unroll
    for (int i = 0; i < NT; ++i) {
        t3[i][0] = -__builtin_inff(); t3[i][1] = -__builtin_inff(); t3[i][2] = -__builtin_inff();
    }

    const f32x16 zq = {0.f,0.f,0.f,0.f,0.f,0.f,0.f,0.f,0.f,0.f,0.f,0.f,0.f,0.f,0.f,0.f};

    // compute tiles [s0, s1)
    auto compute = [&](int s0, int s1) {
        for (int st = s0; st < s1; ++st) {
            const short8* rb = ldsv + st * 256 + l31 * 8;   // row base
            short8 a0 = rb[u[0]];
            short8 a1 = rb[u[1]];
            short8 a2 = rb[u[2]];
            short8 a3 = rb[u[3]];
            #pragma unroll
            for (int i = 0; i < NT; ++i) {
                f32x16 cc = __builtin_amdgcn_mfma_f32_32x32x16_bf16(a0, bq[i][0], zq, 0, 0, 0);
                cc = __builtin_amdgcn_mfma_f32_32x32x16_bf16(a1, bq[i][1], cc, 0, 0, 0);
                cc = __builtin_amdgcn_mfma_f32_32x32x16_bf16(a2, bq[i][2], cc, 0, 0, 0);
                cc = __builtin_amdgcn_mfma_f32_32x32x16_bf16(a3, bq[i][3], cc, 0, 0, 0);
                // 16 -> 1 max3 tree (8 ops); pad rows give 0.0: never top-3
                float m1 = max3f(cc[0],  cc[1],  cc[2]);
                float m2 = max3f(cc[3],  cc[4],  cc[5]);
                float m3 = max3f(cc[6],  cc[7],  cc[8]);
                float m4 = max3f(cc[9],  cc[10], cc[11]);
                float m5 = max3f(cc[12], cc[13], cc[14]);
                float ma = max3f(m1, m2, m3);
                float mb = max3f(m4, m5, cc[15]);
                float m  = fmaxf(ma, mb);
                // 3-op insert
                t3[i][2] = __builtin_amdgcn_fmed3f(m, t3[i][1], t3[i][2]);
                t3[i][1] = __builtin_amdgcn_fmed3f(m, t3[i][0], t3[i][1]);
                t3[i][0] = fmaxf(m, t3[i][0]);
            }
        }
    };

    // ---- pipelined phases: stage Q(k+1) overlapped with compute Q(k) ----
    __syncthreads();                          // Q0 visible
    stage_range(Sfp, ldsv, tid, 2048, 4096);  // rows 256..511
    compute(0, 8);
    __syncthreads();                          // Q1 visible
    stage_range(Sfp, ldsv, tid, 4096, 6144);  // rows 512..767
    compute(8, 16);
    __syncthreads();                          // Q2 visible
    stage_range(Sfp, ldsv, tid, 6144, 7936);  // rows 768..991 (incl pad)
    compute(16, 24);
    __syncthreads();                          // Q3 visible
    compute(24, ST32);

    // ---- merge across the two k-halves (same col, disjoint row sets) ----
    #pragma unroll
    for (int i = 0; i < NT; ++i) {
        float t0 = t3[i][0], t1 = t3[i][1], t2 = t3[i][2];
        float o0 = __shfl_xor(t0, 32, 64);
        float o1 = __shfl_xor(t1, 32, 64);
        float o2 = __shfl_xor(t2, 32, 64);
        t2 = __builtin_amdgcn_fmed3f(o0, t1, t2);
        t1 = __builtin_amdgcn_fmed3f(o0, t0, t1);
        t0 = fmaxf(o0, t0);
        t2 = __builtin_amdgcn_fmed3f(o1, t1, t2);
        t1 = __builtin_amdgcn_fmed3f(o1, t0, t1);
        t0 = fmaxf(o1, t0);
        t2 = __builtin_amdgcn_fmed3f(o2, t1, t2);
        t1 = __builtin_amdgcn_fmed3f(o2, t0, t1);
        t0 = fmaxf(o2, t0);

        float rs = (rows[i] < QROWS && lane < 32) ? (t0 + t1 + t2) : 0.f;
        int qi_l = (rows[i] >= PQ) + (rows[i] >= 2 * PQ);   // 0..2
        #pragma unroll
        for (int q = 0; q < QI_PER_BLK; ++q) {
            float vq = (qi_l == q) ? rs : 0.f;
            vq += __shfl_xor(vq, 1, 64);
            vq += __shfl_xor(vq, 2, 64);
            vq += __shfl_xor(vq, 4, 64);
            vq += __shfl_xor(vq, 8, 64);
            vq += __shfl_xor(vq, 16, 64);
            if (lane == 0 && vq != 0.f) atomicAdd(&sums[q], vq);
        }
    }
}

// Block = (pair, chunk of 3 qi). 512 threads (8 waves). Quarter-pipelined
// fused staging; single dispatch, no workspace.
__global__ __launch_bounds__(512)
__attribute__((amdgpu_waves_per_eu(2)))
void lpc_full(const float* __restrict__ qf, const float* __restrict__ sf,
              float* __restrict__ out) {
    // bijective XCD swizzle: 25 blocks sharing a panel land on few XCDs
    const int gid = blockIdx.x;             // 0..249
    const int qq = NPC / 8, rr = NPC % 8;   // 31, 2
    const int xcd = gid % 8, idx = gid / 8;
    const int blk = (xcd < rr ? xcd * (qq + 1) : rr * (qq + 1) + (xcd - rr) * qq) + idx;

    const int pair  = blk / QCHUNKS;        // b*WAY + w
    const int chunk = blk % QCHUNKS;
    const int b   = pair / WAY, w = pair % WAY;
    const int qi0 = chunk * QI_PER_BLK;
    const int tid  = threadIdx.x;
    const int wid  = tid >> 6;              // 0..7

    __shared__ short8 ldsv[SPAD * 8];       // 126976 B (swizzled layout)
    __shared__ float  sums[QI_PER_BLK];

    if (tid < QI_PER_BLK) sums[tid] = 0.f;

    const float* Sfp = sf + (size_t)pair * SSUP * D_;   // contiguous 980x64 f32
    const float* Qc  = qf + (size_t)(b * NWQ + qi0) * PQ * D_;

    // 19 q-tiles of 32 over 8 waves: waves 0..2 own 3 tiles, waves 3..7 own 2.
    // (Both instantiations execute the same 4 internal barriers.)
    if (wid < QT32 - 2 * NWAVES)            // wid < 3
        wave_path<3>(ldsv, wid, Qc, Sfp, sums);
    else
        wave_path<2>(ldsv, wid, Qc, Sfp, sums);

    __syncthreads();
    if (tid < QI_PER_BLK)
        out[((size_t)b * NWQ + qi0 + tid) * WAY + w] = sums[tid] * (1.0f / (PQ * 3.0f));
}

// ---------------- fp32 fallback (unused safety net) ----------------
__global__ __launch_bounds__(256)
void lpc_kernel(const float* __restrict__ qfea,
                const float* __restrict__ sfea,
                float* __restrict__ out) {
    const int blk = blockIdx.x;
    const int w  = blk % WAY;
    const int qi = (blk / WAY) % NWQ;
    const int b  = blk / (WAY * NWQ);
    const int p  = threadIdx.x;
    float sum3 = 0.0f;
    if (p < PQ) {
        float qreg[D_];
        const float4* q4 = reinterpret_cast<const float4*>(
            qfea + (((size_t)b * NWQ + qi) * PQ + p) * D_);
        #pragma unroll
        for (int i = 0; i < D_ / 4; ++i) {
            float4 v = q4[i];
            qreg[4*i+0] = v.x; qreg[4*i+1] = v.y; qreg[4*i+2] = v.z; qreg[4*i+3] = v.w;
        }
        const float* sbase = sfea + ((size_t)b * WAY + w) * SSUP * D_;
        float t0 = -INFINITY, t1 = -INFINITY, t2 = -INFINITY;
        for (int s = 0; s < SSUP; ++s) {
            const float4* s4 = reinterpret_cast<const float4*>(sbase + (size_t)s * D_);
            float a0 = 0.f, a1 = 0.f, a2 = 0.f, a3 = 0.f;
            #pragma unroll
            for (int i = 0; i < D_ / 4; ++i) {
                float4 v = s4[i];
                a0 = fmaf(qreg[4*i+0], v.x, a0);
                a1 = fmaf(qreg[4*i+1], v.y, a1);
                a2 = fmaf(qreg[4*i+2], v.z, a2);
                a3 = fmaf(qreg[4*i+3], v.w, a3);
            }
            float dot = (a0 + a1) + (a2 + a3);
            float m0 = fminf(dot, t0);  t0 = fmaxf(dot, t0);
            float m1 = fminf(m0, t1);   t1 = fmaxf(m0, t1);
            t2 = fmaxf(m1, t2);
        }
        sum3 = t0 + t1 + t2;
    }
    __shared__ float red[256];
    red[threadIdx.x] = sum3;
    __syncthreads();
    #pragma unroll
    for (int off = 128; off > 0; off >>= 1) {
        if (threadIdx.x < off) red[threadIdx.x] += red[threadIdx.x + off];
        __syncthreads();
    }
    if (threadIdx.x == 0) out[blk] = red[0] * (1.0f / (PQ * 3.0f));
}

extern "C" void kernel_launch(void* const* d_in, const int* in_sizes, int n_in,
                              void* d_out, int out_size, void* d_ws, size_t ws_size,
                              hipStream_t stream) {
    const float* qf = (const float*)d_in[0];   // [2,75,196,64]
    const float* sf = (const float*)d_in[1];   // [2,5,5,196,64]
    float* out = (float*)d_out;                // [150,5]

    (void)d_ws; (void)ws_size;
    lpc_full<<<NPC, 512, 0, stream>>>(qf, sf, out);
}

// Round 21
// 31.354 us; speedup vs baseline: 1.0193x; 1.0193x over previous
//
#include <hip/hip_runtime.h>

#define B_    2
#define NWQ   75
#define PQ    196
#define D_    64
#define WAY   5
#define SSUP  980                  // support patches per (b, way)
#define SPAD  992                  // padded to 31*32
#define ST32  31                   // 32-row support tiles
#define QI_PER_BLK 3
#define QCHUNKS 25                 // 75/3
#define QROWS 588                  // 3*196 query rows per chunk
#define QT32  19                   // ceil(588/32) query tiles of 32
#define NPC  (B_ * WAY * QCHUNKS)  // 250 blocks
#define NWAVES 8                   // waves per block (512 threads)

typedef __attribute__((ext_vector_type(8)))  short short8;   // 8 bf16 = 4 VGPR
typedef __attribute__((ext_vector_type(16))) float f32x16;   // 32x32 acc

__device__ __forceinline__ ushort f2bf(float f) {
    uint u = __builtin_bit_cast(uint, f);
    u = (u + 0x7FFFu + ((u >> 16) & 1u)) >> 16;
    return (ushort)u;
}

__device__ __forceinline__ short8 pack8(float4 a, float4 b) {
    short8 o;
    o[0] = (short)f2bf(a.x); o[1] = (short)f2bf(a.y);
    o[2] = (short)f2bf(a.z); o[3] = (short)f2bf(a.w);
    o[4] = (short)f2bf(b.x); o[5] = (short)f2bf(b.y);
    o[6] = (short)f2bf(b.z); o[7] = (short)f2bf(b.w);
    return o;
}

__device__ __forceinline__ float max3f(float a, float b, float c) {
    return fmaxf(fmaxf(a, b), c);
}

// insert v into descending top-3 (t0 >= t1 >= t2), 3 ops
#define INS3(v, t0, t1, t2)                                   \
    do {                                                      \
        t2 = __builtin_amdgcn_fmed3f((v), (t1), (t2));        \
        t1 = __builtin_amdgcn_fmed3f((v), (t0), (t1));        \
        t0 = fmaxf((v), (t0));                                \
    } while (0)

// Round-21: balanced wave decomposition. Every wave owns 2 FULL q-tile
// streams (tiles wid, wid+8) over all 31 s-tiles, plus a disjoint s-slice
// [31w/8, 31(w+1)/8) of SPLIT q-tiles 16,17,18. Uniform ~74 tile-streams/wave
// vs r19's 93/62 imbalance (-20% critical path). Split partial top-3s merge
// through a 12KB LDS buffer (exact max/med3: order-independent, bit-identical).
// Main loop per tile-stream unchanged: 4x mfma_32x32x16 -> 16->1 max3 screen
// -> 3-op insert. Staging = r19 monolithic (r20's pipelining regressed).
__global__ __launch_bounds__(512)
__attribute__((amdgpu_waves_per_eu(1, 2)))
void lpc_full(const float* __restrict__ qf, const float* __restrict__ sf,
              float* __restrict__ out) {
    // bijective XCD swizzle: 25 blocks sharing a panel land on few XCDs
    const int gid = blockIdx.x;             // 0..249
    const int qq = NPC / 8, rr = NPC % 8;   // 31, 2
    const int xcd = gid % 8, idx = gid / 8;
    const int blk = (xcd < rr ? xcd * (qq + 1) : rr * (qq + 1) + (xcd - rr) * qq) + idx;

    const int pair  = blk / QCHUNKS;        // b*WAY + w
    const int chunk = blk % QCHUNKS;
    const int b   = pair / WAY, w = pair % WAY;
    const int qi0 = chunk * QI_PER_BLK;
    const int tid  = threadIdx.x;
    const int wid  = tid >> 6;              // 0..7
    const int lane = tid & 63;
    const int l31  = lane & 31;             // A row / B col within tile
    const int h    = lane >> 5;             // k-half
    const int l7   = lane & 7;

    __shared__ short8 ldsv[SPAD * 8];       // 126976 B (swizzled layout)
    __shared__ float4 mrg[3][NWAVES][32];   // 12288 B: split-tile partials
    __shared__ float  sums[QI_PER_BLK];

    if (tid < QI_PER_BLK) sums[tid] = 0.f;

    // ---- staging: fp32 global -> bf16 -> swizzled LDS (monolithic, r19) ----
    const float* Sfp = sf + (size_t)pair * SSUP * D_;   // contiguous 980x64 f32
    #pragma unroll
    for (int it = 0; it < 16; ++it) {
        int u_idx = it * 512 + tid;         // 16B unit index, 7936 total
        if (u_idx < SPAD * 8) {
            int r = u_idx >> 3, u = u_idx & 7;
            short8 o = {0,0,0,0,0,0,0,0};
            if (r < SSUP) {
                const float* src = Sfp + (size_t)r * D_ + u * 8;
                float4 f0 = *(const float4*)src;
                float4 f1 = *(const float4*)(src + 4);
                o = pack8(f0, f1);
            }
            ldsv[(r << 3) | (u ^ (r & 7))] = o;
        }
    }

    const float* Qc = qf + (size_t)(b * NWQ + qi0) * PQ * D_;

    int u[4];
    #pragma unroll
    for (int j = 0; j < 4; ++j) u[j] = (j * 2 + h) ^ l7;   // swizzled 16B unit

    // ---- B fragments: 2 full + 3 split streams (fp32 -> bf16 in regs) ----
    short8 bq[5][4];
    int rows[5];
    #pragma unroll
    for (int i = 0; i < 5; ++i) {
        int qt = (i < 2) ? (wid + NWAVES * i) : (16 + (i - 2));
        int row = qt * 32 + l31;
        rows[i] = row;
        int rc = (row < QROWS) ? row : 0;   // clamp; discarded at epilogue
        const float* qrow = Qc + (size_t)rc * D_;
        #pragma unroll
        for (int j = 0; j < 4; ++j) {
            const float* s = qrow + h * 8 + j * 16;
            float4 f0 = *(const float4*)s;
            float4 f1 = *(const float4*)(s + 4);
            bq[i][j] = pack8(f0, f1);
        }
    }

    float t3[5][3];
    #pragma unroll
    for (int i = 0; i < 5; ++i) {
        t3[i][0] = -__builtin_inff(); t3[i][1] = -__builtin_inff(); t3[i][2] = -__builtin_inff();
    }

    const f32x16 zq = {0.f,0.f,0.f,0.f,0.f,0.f,0.f,0.f,0.f,0.f,0.f,0.f,0.f,0.f,0.f,0.f};

    __syncthreads();                        // panel + q-frags ready

    // this wave's split s-range: [31w/8, 31(w+1)/8)  -> counts 3,4,4,4,4,4,4,4
    const int s_lo = (wid * ST32) >> 3;
    const int s_hi = ((wid + 1) * ST32) >> 3;

    // ---- 31 support tiles of 32 rows ----
    for (int st = 0; st < ST32; ++st) {
        const short8* rb = ldsv + st * 256 + l31 * 8;   // row base (8 units/row)
        short8 a0 = rb[u[0]];
        short8 a1 = rb[u[1]];
        short8 a2 = rb[u[2]];
        short8 a3 = rb[u[3]];

        // one tile-stream: 4 MFMA -> 16->1 max3 screen -> insert
        auto stream = [&](int i) {
            f32x16 cc = __builtin_amdgcn_mfma_f32_32x32x16_bf16(a0, bq[i][0], zq, 0, 0, 0);
            cc = __builtin_amdgcn_mfma_f32_32x32x16_bf16(a1, bq[i][1], cc, 0, 0, 0);
            cc = __builtin_amdgcn_mfma_f32_32x32x16_bf16(a2, bq[i][2], cc, 0, 0, 0);
            cc = __builtin_amdgcn_mfma_f32_32x32x16_bf16(a3, bq[i][3], cc, 0, 0, 0);
            float m1 = max3f(cc[0],  cc[1],  cc[2]);
            float m2 = max3f(cc[3],  cc[4],  cc[5]);
            float m3 = max3f(cc[6],  cc[7],  cc[8]);
            float m4 = max3f(cc[9],  cc[10], cc[11]);
            float m5 = max3f(cc[12], cc[13], cc[14]);
            float ma = max3f(m1, m2, m3);
            float mb = max3f(m4, m5, cc[15]);
            float m  = fmaxf(ma, mb);       // pad rows give 0.0: never top-3
            INS3(m, t3[i][0], t3[i][1], t3[i][2]);
        };

        stream(0);
        stream(1);
        if (st >= s_lo && st < s_hi) {      // wave-uniform branch
            stream(2); stream(3); stream(4);
        }
    }

    // ---- full streams: k-half merge + per-qi accumulate ----
    #pragma unroll
    for (int i = 0; i < 2; ++i) {
        float t0 = t3[i][0], t1 = t3[i][1], t2 = t3[i][2];
        float o0 = __shfl_xor(t0, 32, 64);
        float o1 = __shfl_xor(t1, 32, 64);
        float o2 = __shfl_xor(t2, 32, 64);
        INS3(o0, t0, t1, t2);
        INS3(o1, t0, t1, t2);
        INS3(o2, t0, t1, t2);

        float rs = (rows[i] < QROWS && lane < 32) ? (t0 + t1 + t2) : 0.f;
        int qi_l = (rows[i] >= PQ) + (rows[i] >= 2 * PQ);   // 0..2
        #pragma unroll
        for (int q = 0; q < QI_PER_BLK; ++q) {
            float vq = (qi_l == q) ? rs : 0.f;
            vq += __shfl_xor(vq, 1, 64);
            vq += __shfl_xor(vq, 2, 64);
            vq += __shfl_xor(vq, 4, 64);
            vq += __shfl_xor(vq, 8, 64);
            vq += __shfl_xor(vq, 16, 64);
            if (lane == 0 && vq != 0.f) atomicAdd(&sums[q], vq);
        }
    }

    // ---- split streams: k-half merge, store partial top-3 ----
    #pragma unroll
    for (int j = 0; j < 3; ++j) {
        float t0 = t3[2 + j][0], t1 = t3[2 + j][1], t2 = t3[2 + j][2];
        float o0 = __shfl_xor(t0, 32, 64);
        float o1 = __shfl_xor(t1, 32, 64);
        float o2 = __shfl_xor(t2, 32, 64);
        INS3(o0, t0, t1, t2);
        INS3(o1, t0, t1, t2);
        INS3(o2, t0, t1, t2);
        if (lane < 32) mrg[j][wid][l31] = float4{t0, t1, t2, 0.f};
    }
    __syncthreads();

    // ---- waves 0..2 merge the 8 partials of split tile (16 + wid) ----
    if (wid < 3) {
        int row = (16 + wid) * 32 + l31;
        float t0 = -__builtin_inff(), t1 = -__builtin_inff(), t2 = -__builtin_inff();
        if (lane < 32) {
            #pragma unroll
            for (int s = 0; s < NWAVES; ++s) {
                float4 v = mrg[wid][s][l31];
                INS3(v.x, t0, t1, t2);
                INS3(v.y, t0, t1, t2);
                INS3(v.z, t0, t1, t2);
            }
        }
        float rs = (row < QROWS && lane < 32) ? (t0 + t1 + t2) : 0.f;
        int qi_l = (row >= PQ) + (row >= 2 * PQ);   // 0..2
        #pragma unroll
        for (int q = 0; q < QI_PER_BLK; ++q) {
            float vq = (qi_l == q) ? rs : 0.f;
            vq += __shfl_xor(vq, 1, 64);
            vq += __shfl_xor(vq, 2, 64);
            vq += __shfl_xor(vq, 4, 64);
            vq += __shfl_xor(vq, 8, 64);
            vq += __shfl_xor(vq, 16, 64);
            if (lane == 0 && vq != 0.f) atomicAdd(&sums[q], vq);
        }
    }

    __syncthreads();
    if (tid < QI_PER_BLK)
        out[((size_t)b * NWQ + qi0 + tid) * WAY + w] = sums[tid] * (1.0f / (PQ * 3.0f));
}

// ---------------- fp32 fallback (unused safety net) ----------------
__global__ __launch_bounds__(256)
void lpc_kernel(const float* __restrict__ qfea,
                const float* __restrict__ sfea,
                float* __restrict__ out) {
    const int blk = blockIdx.x;
    const int w  = blk % WAY;
    const int qi = (blk / WAY) % NWQ;
    const int b  = blk / (WAY * NWQ);
    const int p  = threadIdx.x;
    float sum3 = 0.0f;
    if (p < PQ) {
        float qreg[D_];
        const float4* q4 = reinterpret_cast<const float4*>(
            qfea + (((size_t)b * NWQ + qi) * PQ + p) * D_);
        #pragma unroll
        for (int i = 0; i < D_ / 4; ++i) {
            float4 v = q4[i];
            qreg[4*i+0] = v.x; qreg[4*i+1] = v.y; qreg[4*i+2] = v.z; qreg[4*i+3] = v.w;
        }
        const float* sbase = sfea + ((size_t)b * WAY + w) * SSUP * D_;
        float t0 = -INFINITY, t1 = -INFINITY, t2 = -INFINITY;
        for (int s = 0; s < SSUP; ++s) {
            const float4* s4 = reinterpret_cast<const float4*>(sbase + (size_t)s * D_);
            float a0 = 0.f, a1 = 0.f, a2 = 0.f, a3 = 0.f;
            #pragma unroll
            for (int i = 0; i < D_ / 4; ++i) {
                float4 v = s4[i];
                a0 = fmaf(qreg[4*i+0], v.x, a0);
                a1 = fmaf(qreg[4*i+1], v.y, a1);
                a2 = fmaf(qreg[4*i+2], v.z, a2);
                a3 = fmaf(qreg[4*i+3], v.w, a3);
            }
            float dot = (a0 + a1) + (a2 + a3);
            float m0 = fminf(dot, t0);  t0 = fmaxf(dot, t0);
            float m1 = fminf(m0, t1);   t1 = fmaxf(m0, t1);
            t2 = fmaxf(m1, t2);
        }
        sum3 = t0 + t1 + t2;
    }
    __shared__ float red[256];
    red[threadIdx.x] = sum3;
    __syncthreads();
    #pragma unroll
    for (int off = 128; off > 0; off >>= 1) {
        if (threadIdx.x < off) red[threadIdx.x] += red[threadIdx.x + off];
        __syncthreads();
    }
    if (threadIdx.x == 0) out[blk] = red[0] * (1.0f / (PQ * 3.0f));
}

extern "C" void kernel_launch(void* const* d_in, const int* in_sizes, int n_in,
                              void* d_out, int out_size, void* d_ws, size_t ws_size,
                              hipStream_t stream) {
    const float* qf = (const float*)d_in[0];   // [2,75,196,64]
    const float* sf = (const float*)d_in[1];   // [2,5,5,196,64]
    float* out = (float*)d_out;                // [150,5]

    (void)d_ws; (void)ws_size;
    lpc_full<<<NPC, 512, 0, stream>>>(qf, sf, out);
}

// Round 22
// 26.351 us; speedup vs baseline: 1.2129x; 1.1899x over previous
//
#include <hip/hip_runtime.h>

#define B_    2
#define NWQ   75
#define PQ    196
#define D_    64
#define WAY   5
#define SSUP  980                  // support patches per (b, way)
#define SPAD  992                  // padded to 31*32
#define ST32  31                   // 32-row support tiles
#define QI_PER_BLK 3
#define QCHUNKS 25                 // 75/3
#define QROWS 588                  // 3*196 query rows per chunk
#define QT32  19                   // ceil(588/32) query tiles of 32
#define NPC  (B_ * WAY * QCHUNKS)  // 250 blocks
#define NWAVES 8                   // waves per block (512 threads)

typedef __attribute__((ext_vector_type(8)))  short short8;   // 8 bf16 = 4 VGPR
typedef __attribute__((ext_vector_type(16))) float f32x16;   // 32x32 acc

__device__ __forceinline__ ushort f2bf(float f) {
    uint u = __builtin_bit_cast(uint, f);
    u = (u + 0x7FFFu + ((u >> 16) & 1u)) >> 16;
    return (ushort)u;
}

__device__ __forceinline__ short8 pack8(float4 a, float4 b) {
    short8 o;
    o[0] = (short)f2bf(a.x); o[1] = (short)f2bf(a.y);
    o[2] = (short)f2bf(a.z); o[3] = (short)f2bf(a.w);
    o[4] = (short)f2bf(b.x); o[5] = (short)f2bf(b.y);
    o[6] = (short)f2bf(b.z); o[7] = (short)f2bf(b.w);
    return o;
}

__device__ __forceinline__ float max3f(float a, float b, float c) {
    return fmaxf(fmaxf(a, b), c);
}

// Best-known configuration (round 19, 26.5 us): single kernel, fused staging
// (fp32 global -> bf16 -> swizzled LDS in the prologue), 32x32x16 MFMA main
// loop with 16->1 max3 screening and a 3-op med3 top-3 insert.
template<int NT>
__device__ __forceinline__ void wave_path(
    const short8* __restrict__ ldsv, int wid,
    const float* __restrict__ Qc, float* __restrict__ sums) {

    const int lane = threadIdx.x & 63;
    const int l31  = lane & 31;               // A row / B col within tile
    const int h    = lane >> 5;               // k-half
    const int l7   = lane & 7;

    int u[4];
    #pragma unroll
    for (int j = 0; j < 4; ++j) u[j] = (j * 2 + h) ^ l7;   // swizzled 16B unit

    // ---- B fragments: NT streams x 4 k-step frags (fp32 -> bf16 in regs) ----
    short8 bq[NT][4];
    int rows[NT];
    #pragma unroll
    for (int i = 0; i < NT; ++i) {
        int row = (wid + NWAVES * i) * 32 + l31;
        rows[i] = row;
        int rc = (row < QROWS) ? row : 0;     // clamp; discarded at epilogue
        const float* qrow = Qc + (size_t)rc * D_;
        #pragma unroll
        for (int j = 0; j < 4; ++j) {
            const float* s = qrow + h * 8 + j * 16;
            float4 f0 = *(const float4*)s;
            float4 f1 = *(const float4*)(s + 4);
            bq[i][j] = pack8(f0, f1);
        }
    }

    float t3[NT][3];
    #pragma unroll
    for (int i = 0; i < NT; ++i) {
        t3[i][0] = -__builtin_inff(); t3[i][1] = -__builtin_inff(); t3[i][2] = -__builtin_inff();
    }

    const f32x16 zq = {0.f,0.f,0.f,0.f,0.f,0.f,0.f,0.f,0.f,0.f,0.f,0.f,0.f,0.f,0.f,0.f};

    // staging ds_writes + q loads drained by the barrier (compiler waits)
    __syncthreads();

    // ---- 31 support tiles of 32 rows ----
    for (int st = 0; st < ST32; ++st) {
        const short8* rb = ldsv + st * 256 + l31 * 8;   // row base (8 units/row)
        short8 a0 = rb[u[0]];
        short8 a1 = rb[u[1]];
        short8 a2 = rb[u[2]];
        short8 a3 = rb[u[3]];
        #pragma unroll
        for (int i = 0; i < NT; ++i) {
            f32x16 cc = __builtin_amdgcn_mfma_f32_32x32x16_bf16(a0, bq[i][0], zq, 0, 0, 0);
            cc = __builtin_amdgcn_mfma_f32_32x32x16_bf16(a1, bq[i][1], cc, 0, 0, 0);
            cc = __builtin_amdgcn_mfma_f32_32x32x16_bf16(a2, bq[i][2], cc, 0, 0, 0);
            cc = __builtin_amdgcn_mfma_f32_32x32x16_bf16(a3, bq[i][3], cc, 0, 0, 0);
            // 16 -> 1 max3 tree (8 ops); pad rows give 0.0: never top-3
            float m1 = max3f(cc[0],  cc[1],  cc[2]);
            float m2 = max3f(cc[3],  cc[4],  cc[5]);
            float m3 = max3f(cc[6],  cc[7],  cc[8]);
            float m4 = max3f(cc[9],  cc[10], cc[11]);
            float m5 = max3f(cc[12], cc[13], cc[14]);
            float ma = max3f(m1, m2, m3);
            float mb = max3f(m4, m5, cc[15]);
            float m  = fmaxf(ma, mb);
            // 3-op insert
            t3[i][2] = __builtin_amdgcn_fmed3f(m, t3[i][1], t3[i][2]);
            t3[i][1] = __builtin_amdgcn_fmed3f(m, t3[i][0], t3[i][1]);
            t3[i][0] = fmaxf(m, t3[i][0]);
        }
    }

    // ---- merge across the two k-halves (same col, disjoint row sets) ----
    #pragma unroll
    for (int i = 0; i < NT; ++i) {
        float t0 = t3[i][0], t1 = t3[i][1], t2 = t3[i][2];
        float o0 = __shfl_xor(t0, 32, 64);
        float o1 = __shfl_xor(t1, 32, 64);
        float o2 = __shfl_xor(t2, 32, 64);
        t2 = __builtin_amdgcn_fmed3f(o0, t1, t2);
        t1 = __builtin_amdgcn_fmed3f(o0, t0, t1);
        t0 = fmaxf(o0, t0);
        t2 = __builtin_amdgcn_fmed3f(o1, t1, t2);
        t1 = __builtin_amdgcn_fmed3f(o1, t0, t1);
        t0 = fmaxf(o1, t0);
        t2 = __builtin_amdgcn_fmed3f(o2, t1, t2);
        t1 = __builtin_amdgcn_fmed3f(o2, t0, t1);
        t0 = fmaxf(o2, t0);

        float rs = (rows[i] < QROWS && lane < 32) ? (t0 + t1 + t2) : 0.f;
        int qi_l = (rows[i] >= PQ) + (rows[i] >= 2 * PQ);   // 0..2
        #pragma unroll
        for (int q = 0; q < QI_PER_BLK; ++q) {
            float vq = (qi_l == q) ? rs : 0.f;
            vq += __shfl_xor(vq, 1, 64);
            vq += __shfl_xor(vq, 2, 64);
            vq += __shfl_xor(vq, 4, 64);
            vq += __shfl_xor(vq, 8, 64);
            vq += __shfl_xor(vq, 16, 64);
            if (lane == 0 && vq != 0.f) atomicAdd(&sums[q], vq);
        }
    }
}

// Block = (pair, chunk of 3 qi). 512 threads (8 waves). Fused staging:
// fp32 panel -> bf16 swizzled LDS in the prologue (no cvt kernel, no ws).
__global__ __launch_bounds__(512)
__attribute__((amdgpu_waves_per_eu(2)))
void lpc_full(const float* __restrict__ qf, const float* __restrict__ sf,
              float* __restrict__ out) {
    // bijective XCD swizzle: 25 blocks sharing a panel land on few XCDs
    const int gid = blockIdx.x;             // 0..249
    const int qq = NPC / 8, rr = NPC % 8;   // 31, 2
    const int xcd = gid % 8, idx = gid / 8;
    const int blk = (xcd < rr ? xcd * (qq + 1) : rr * (qq + 1) + (xcd - rr) * qq) + idx;

    const int pair  = blk / QCHUNKS;        // b*WAY + w
    const int chunk = blk % QCHUNKS;
    const int b   = pair / WAY, w = pair % WAY;
    const int qi0 = chunk * QI_PER_BLK;
    const int tid  = threadIdx.x;
    const int wid  = tid >> 6;              // 0..7

    __shared__ short8 ldsv[SPAD * 8];       // 126976 B (swizzled layout)
    __shared__ float  sums[QI_PER_BLK];

    if (tid < QI_PER_BLK) sums[tid] = 0.f;

    // ---- fused staging: fp32 global -> bf16 -> swizzled ds_write_b128 ----
    const float* Sfp = sf + (size_t)pair * SSUP * D_;   // contiguous 980x64 f32
    #pragma unroll
    for (int it = 0; it < 16; ++it) {
        int u_idx = it * 512 + tid;         // 16B unit index, 7936 total
        if (u_idx < SPAD * 8) {
            int r = u_idx >> 3, u = u_idx & 7;
            short8 o = {0,0,0,0,0,0,0,0};
            if (r < SSUP) {
                const float* src = Sfp + (size_t)r * D_ + u * 8;
                float4 f0 = *(const float4*)src;
                float4 f1 = *(const float4*)(src + 4);
                o = pack8(f0, f1);
            }
            ldsv[(r << 3) | (u ^ (r & 7))] = o;
        }
    }

    const float* Qc = qf + (size_t)(b * NWQ + qi0) * PQ * D_;

    // 19 q-tiles of 32 over 8 waves: waves 0..2 own 3 tiles, waves 3..7 own 2.
    if (wid < QT32 - 2 * NWAVES)            // wid < 3
        wave_path<3>(ldsv, wid, Qc, sums);
    else
        wave_path<2>(ldsv, wid, Qc, sums);

    __syncthreads();
    if (tid < QI_PER_BLK)
        out[((size_t)b * NWQ + qi0 + tid) * WAY + w] = sums[tid] * (1.0f / (PQ * 3.0f));
}

// ---------------- fp32 fallback (unused safety net) ----------------
__global__ __launch_bounds__(256)
void lpc_kernel(const float* __restrict__ qfea,
                const float* __restrict__ sfea,
                float* __restrict__ out) {
    const int blk = blockIdx.x;
    const int w  = blk % WAY;
    const int qi = (blk / WAY) % NWQ;
    const int b  = blk / (WAY * NWQ);
    const int p  = threadIdx.x;
    float sum3 = 0.0f;
    if (p < PQ) {
        float qreg[D_];
        const float4* q4 = reinterpret_cast<const float4*>(
            qfea + (((size_t)b * NWQ + qi) * PQ + p) * D_);
        #pragma unroll
        for (int i = 0; i < D_ / 4; ++i) {
            float4 v = q4[i];
            qreg[4*i+0] = v.x; qreg[4*i+1] = v.y; qreg[4*i+2] = v.z; qreg[4*i+3] = v.w;
        }
        const float* sbase = sfea + ((size_t)b * WAY + w) * SSUP * D_;
        float t0 = -INFINITY, t1 = -INFINITY, t2 = -INFINITY;
        for (int s = 0; s < SSUP; ++s) {
            const float4* s4 = reinterpret_cast<const float4*>(sbase + (size_t)s * D_);
            float a0 = 0.f, a1 = 0.f, a2 = 0.f, a3 = 0.f;
            #pragma unroll
            for (int i = 0; i < D_ / 4; ++i) {
                float4 v = s4[i];
                a0 = fmaf(qreg[4*i+0], v.x, a0);
                a1 = fmaf(qreg[4*i+1], v.y, a1);
                a2 = fmaf(qreg[4*i+2], v.z, a2);
                a3 = fmaf(qreg[4*i+3], v.w, a3);
            }
            float dot = (a0 + a1) + (a2 + a3);
            float m0 = fminf(dot, t0);  t0 = fmaxf(dot, t0);
            float m1 = fminf(m0, t1);   t1 = fmaxf(m0, t1);
            t2 = fmaxf(m1, t2);
        }
        sum3 = t0 + t1 + t2;
    }
    __shared__ float red[256];
    red[threadIdx.x] = sum3;
    __syncthreads();
    #pragma unroll
    for (int off = 128; off > 0; off >>= 1) {
        if (threadIdx.x < off) red[threadIdx.x] += red[threadIdx.x + off];
        __syncthreads();
    }
    if (threadIdx.x == 0) out[blk] = red[0] * (1.0f / (PQ * 3.0f));
}

extern "C" void kernel_launch(void* const* d_in, const int* in_sizes, int n_in,
                              void* d_out, int out_size, void* d_ws, size_t ws_size,
                              hipStream_t stream) {
    const float* qf = (const float*)d_in[0];   // [2,75,196,64]
    const float* sf = (const float*)d_in[1];   // [2,5,5,196,64]
    float* out = (float*)d_out;                // [150,5]

    (void)d_ws; (void)ws_size;
    lpc_full<<<NPC, 512, 0, stream>>>(qf, sf, out);
}